// Round 1
// baseline (2715.360 us; speedup 1.0000x reference)
//
#include <hip/hip_runtime.h>
#include <hip/hip_bf16.h>

// RecursiveNet: 18 stages of {conv1d(256->128,K=2), +bias, leaky_relu(0.2), maxpool(2,2)}
// on a gathered transpose of x (524288 x 128). The depth-embedding channels are
// time-constant -> folded into a per-stage effective bias.
//
// Buffers live in d_ws, layout [position][128 channels] (column = 512 B contiguous):
//   Bst : 18*128 fp32 effective biases
//   R0  : max 262143 cols (stage outputs for even i)
//   R1  : max 131071 cols (stage outputs for odd i)
// Total ws needed ~ 192 MB.

#define C128 128
#define TP   32        // pooled outputs per block
#define NCOL 65        // input columns needed: 2*TP + 1
#define XSTR 68        // xs_t column stride (words): 16B aligned, 2-way-bank-free on tg reads
#define CK   16        // c-chunk for weight staging
#define WSTR 132       // ws0/ws1 stride (words)

// ---------------------------------------------------------------------------
// Per-stage effective bias: B[i][o] = b[o] + sum_c depth[i][c]*(W[o][128+c][0]+W[o][128+c][1])
__global__ void bias_kernel(const float* __restrict__ W, const float* __restrict__ b,
                            const float* __restrict__ depth, float* __restrict__ Bst) {
    int i = blockIdx.x;    // stage
    int o = threadIdx.x;   // out channel
    const float* Wo = W + (size_t)o * 512 + 256;  // W[o][128+c][k] -> offset 256 + 2c
    const float* di = depth + (size_t)i * 128;
    float s = b[o];
#pragma unroll 8
    for (int c = 0; c < 128; ++c) {
        s += di[c] * (Wo[2 * c] + Wo[2 * c + 1]);
    }
    Bst[i * 128 + o] = s;
}

// ---------------------------------------------------------------------------
// One stage: Y[u][o] = max over s in {0,1} of leaky(W0.X[:,2u+s] + W1.X[:,2u+s+1] + B[o])
// Block: 256 threads = 32 o-groups (4 ch each) x 8 t-groups (8 conv pos each).
__global__ __launch_bounds__(256)
void stage_kernel(const float* __restrict__ Xin,   // [Lin][128] (unused for stage0)
                  const float* __restrict__ x0,    // raw x [N][128] (stage0)
                  const int* __restrict__ perm,    // [N] (stage0)
                  const float* __restrict__ W,     // [128][256][2]
                  const float* __restrict__ Bst,   // [128] effective bias, this stage
                  float* __restrict__ Y,           // [Lp][128]
                  int Lin, int Lp, int stage0) {
    __shared__ float xs[C128 * XSTR];       // xs[c*XSTR + col]  (transposed tile)
    __shared__ float ws0[CK * WSTR];        // ws0[c*WSTR + o]
    __shared__ float ws1[CK * WSTR];

    const int tid = threadIdx.x;
    const int u0 = blockIdx.x * TP;
    const int t0 = u0 * 2;

    // ---- load x tile: NCOL cols x 128 ch. Each iter: one float4 (4 channels) of one col.
    for (int idx = tid; idx < NCOL * 32; idx += 256) {
        int col = idx >> 5;       // 0..64
        int cq = idx & 31;        // channel quad
        int t = t0 + col;
        if (t < Lin) {
            const float* src = stage0 ? (x0 + (size_t)perm[t] * C128 + cq * 4)
                                      : (Xin + (size_t)t * C128 + cq * 4);
            float4 v = *(const float4*)src;
            xs[(cq * 4 + 0) * XSTR + col] = v.x;
            xs[(cq * 4 + 1) * XSTR + col] = v.y;
            xs[(cq * 4 + 2) * XSTR + col] = v.z;
            xs[(cq * 4 + 3) * XSTR + col] = v.w;
        }
    }

    const int og = tid >> 3;      // 0..31
    const int tg = tid & 7;       // 0..7
    const int o0 = og * 4;
    const int tl = tg * 8;        // local conv-position base

    float acc[4][8];
#pragma unroll
    for (int j = 0; j < 4; ++j)
#pragma unroll
        for (int s = 0; s < 8; ++s) acc[j][s] = 0.f;

    for (int kc = 0; kc < C128; kc += CK) {
        __syncthreads();
        // stage weight chunk: all 128 o, CK c's, both taps. float2 per (o,c).
        for (int idx = tid; idx < C128 * CK; idx += 256) {
            int o = idx >> 4;         // /CK
            int c = idx & (CK - 1);
            float2 w = *(const float2*)&W[(size_t)o * 512 + (size_t)(kc + c) * 2];
            ws0[c * WSTR + o] = w.x;
            ws1[c * WSTR + o] = w.y;
        }
        __syncthreads();
#pragma unroll
        for (int c = 0; c < CK; ++c) {
            float4 w0 = *(const float4*)&ws0[c * WSTR + o0];
            float4 w1 = *(const float4*)&ws1[c * WSTR + o0];
            const float* xp = &xs[(kc + c) * XSTR + tl];
            float4 xa = *(const float4*)(xp);       // cols tl..tl+3
            float4 xb = *(const float4*)(xp + 4);   // cols tl+4..tl+7
            float x8 = xp[8];                       // col tl+8
            float xv[9] = {xa.x, xa.y, xa.z, xa.w, xb.x, xb.y, xb.z, xb.w, x8};
#pragma unroll
            for (int s = 0; s < 8; ++s) {
                float a = xv[s], bq = xv[s + 1];
                acc[0][s] += w0.x * a + w1.x * bq;
                acc[1][s] += w0.y * a + w1.y * bq;
                acc[2][s] += w0.z * a + w1.z * bq;
                acc[3][s] += w0.w * a + w1.w * bq;
            }
        }
    }

    // ---- epilogue: bias, leaky, pool(2,2), store
    float bias[4];
#pragma unroll
    for (int j = 0; j < 4; ++j) bias[j] = Bst[o0 + j];

#pragma unroll
    for (int s2 = 0; s2 < 4; ++s2) {
        int u = u0 + tg * 4 + s2;
        if (u < Lp) {
            float4 r;
            float* rp = &r.x;
#pragma unroll
            for (int j = 0; j < 4; ++j) {
                float y0 = acc[j][2 * s2] + bias[j];
                float y1 = acc[j][2 * s2 + 1] + bias[j];
                y0 = (y0 >= 0.f) ? y0 : 0.2f * y0;
                y1 = (y1 >= 0.f) ? y1 : 0.2f * y1;
                rp[j] = fmaxf(y0, y1);
            }
            *(float4*)&Y[(size_t)u * C128 + o0] = r;
        }
    }
}

// ---------------------------------------------------------------------------
extern "C" void kernel_launch(void* const* d_in, const int* in_sizes, int n_in,
                              void* d_out, int out_size, void* d_ws, size_t ws_size,
                              hipStream_t stream) {
    const float* x     = (const float*)d_in[0];   // [524288][128]
    const float* depth = (const float*)d_in[1];   // [32][128]
    const float* W     = (const float*)d_in[2];   // [128][256][2]
    const float* b     = (const float*)d_in[3];   // [128]
    const int*   perm  = (const int*)d_in[4];     // [524288]
    float* out = (float*)d_out;                   // [1][128]

    char* ws = (char*)d_ws;
    float* Bst = (float*)ws;                                          // 18*128 fp32
    float* R0 = (float*)(ws + 16384);                                 // 262143*512 B
    float* R1 = (float*)(ws + 16384 + (size_t)262143 * 512);          // 131071*512 B
    // total ws needed: 16384 + 134217216 + 67108352 ~= 192 MB

    bias_kernel<<<18, 128, 0, stream>>>(W, b, depth, Bst);

    int Lin = 524288;
    const float* in = nullptr;
    for (int i = 0; Lin > 1; ++i) {
        int Lp = (Lin - 1) >> 1;
        float* outp = (Lp == 1) ? out : ((i & 1) ? R1 : R0);
        int blocks = (Lp + TP - 1) / TP;
        stage_kernel<<<blocks, 256, 0, stream>>>(in, x, perm, W, Bst + i * 128,
                                                 outp, Lin, Lp, (i == 0) ? 1 : 0);
        in = outp;
        Lin = Lp;
    }
}

// Round 2
// 632.752 us; speedup vs baseline: 4.2913x; 4.2913x over previous
//
#include <hip/hip_runtime.h>
#include <hip/hip_bf16.h>

// RecursiveNet via bf16 MFMA. 18 stages of y[o,t]=sum_c W0[o,c]X[c,t]+W1[o,c]X[c,t+1]
// (+fp32 folded bias, leaky 0.2, maxpool2). A=[W0|W1] (128x256 bf16) lives in
// registers per wave; intermediates are bf16 [pos][128ch] in ws; B fragments come
// from an XOR-swizzled LDS x-tile. Pool = shfl_xor(1) in MFMA C-layout.

typedef __bf16 v8bf __attribute__((ext_vector_type(8)));
typedef float v16f __attribute__((ext_vector_type(16)));

#define NBCONV 128     // conv positions per block
#define NROWS  129     // staged x rows (NBCONV+1)
#define NTILES 4       // 32-position MFMA N-tiles per block

__device__ __forceinline__ ushort f2bf(float f) {
    __hip_bfloat16 h = __float2bfloat16(f);
    return *reinterpret_cast<ushort*>(&h);
}
__device__ __forceinline__ float bf2f(ushort u) {
    __hip_bfloat16 h;
    *reinterpret_cast<ushort*>(&h) = u;
    return __bfloat162float(h);
}
__device__ __forceinline__ unsigned pack2(float lo, float hi) {
    return (unsigned)f2bf(lo) | ((unsigned)f2bf(hi) << 16);
}

// ---------------------------------------------------------------------------
// Effective bias per stage (fp32, exact): B[i][o] = b[o] + sum_c depth[i][c]*(W[o][128+c][0]+W[o][128+c][1])
__global__ void bias_kernel(const float* __restrict__ W, const float* __restrict__ b,
                            const float* __restrict__ depth, float* __restrict__ Bst) {
    int i = blockIdx.x, o = threadIdx.x;
    const float* Wo = W + (size_t)o * 512 + 256;
    const float* di = depth + (size_t)i * 128;
    float s = b[o];
#pragma unroll 8
    for (int c = 0; c < 128; ++c) s += di[c] * (Wo[2 * c] + Wo[2 * c + 1]);
    Bst[i * 128 + o] = s;
}

// A[o][c] bf16, c<128 -> W[o][c][0], else W[o][c-128][1]
__global__ void repack_kernel(const float* __restrict__ W, ushort* __restrict__ A) {
    int o = blockIdx.x, c = threadIdx.x;
    float v = (c < 128) ? W[(size_t)o * 512 + 2 * c] : W[(size_t)o * 512 + 2 * (c - 128) + 1];
    A[o * 256 + c] = f2bf(v);
}

// ---------------------------------------------------------------------------
__global__ __launch_bounds__(256)
void stage_mfma(const ushort* __restrict__ Xin,  // bf16 [Lin][128] (stage>0)
                const float* __restrict__ x0,    // fp32 [N][128] (stage0)
                const int* __restrict__ perm,    // [N] (stage0)
                const ushort* __restrict__ A,    // bf16 [128][256]
                const float* __restrict__ Bst,   // fp32 [128] this stage
                ushort* __restrict__ Y,          // bf16 [Lp][128]
                float* __restrict__ out_f,       // fp32 [128] (final stage)
                int Lin, int Lp, int stage0, int final) {
    __shared__ ushort xs[NROWS * 128];  // [row][128ch], 16B chunks XOR-swizzled by row&15
    __shared__ ushort ps[16 * 128];     // pooled transpose tile
    __shared__ int prow[NROWS];

    const int tid = threadIdx.x;
    const int u0 = blockIdx.x * (NBCONV / 2);
    const int t0 = u0 * 2;

    if (stage0) {
        for (int r = tid; r < NROWS; r += 256) {
            int t = t0 + r;
            prow[r] = (t < Lin) ? perm[t] : 0;
        }
        __syncthreads();
    }
    // stage x tile: one 16B chunk (8 ch) per iteration per thread
    for (int idx = tid; idx < NROWS * 16; idx += 256) {
        int row = idx >> 4, ck = idx & 15;
        int t = t0 + row;
        int dst = row * 128 + ((ck ^ (row & 15)) * 8);
        if (t < Lin) {
            if (stage0) {
                const float* s = x0 + (size_t)prow[row] * 128 + ck * 8;
                float4 a = *(const float4*)s;
                float4 bq = *(const float4*)(s + 4);
                uint4 v;
                v.x = pack2(a.x, a.y);  v.y = pack2(a.z, a.w);
                v.z = pack2(bq.x, bq.y); v.w = pack2(bq.z, bq.w);
                *(uint4*)&xs[dst] = v;
            } else {
                *(uint4*)&xs[dst] = *(const uint4*)&Xin[(size_t)t * 128 + ck * 8];
            }
        } else {
            uint4 z = {0u, 0u, 0u, 0u};
            *(uint4*)&xs[dst] = z;
        }
    }
    __syncthreads();

    const int lane = tid & 63;
    const int w = tid >> 6;        // wave -> M-tile (out channels 32w..32w+31)
    const int n31 = lane & 31;
    const int h = lane >> 5;

    // A fragments for all 16 K-steps, persistent in VGPRs (64 regs)
    v8bf af[16];
    {
        const ushort* Arow = A + (size_t)(w * 32 + n31) * 256 + h * 8;
#pragma unroll
        for (int s = 0; s < 16; ++s) af[s] = *(const v8bf*)&Arow[s * 16];
    }
    // bias in C-layout register order
    float bias_r[16];
#pragma unroll
    for (int r = 0; r < 16; ++r) bias_r[r] = Bst[w * 32 + (r & 3) + 8 * (r >> 2) + 4 * h];

    for (int nt = 0; nt < NTILES; ++nt) {
        const int row0 = nt * 32 + n31;           // tap-0 row for this lane's column
        const ushort* xr0 = &xs[row0 * 128];
        const ushort* xr1 = &xs[(row0 + 1) * 128];
        const int m0 = row0 & 15, m1 = (row0 + 1) & 15;
        v16f acc = {0.f, 0.f, 0.f, 0.f, 0.f, 0.f, 0.f, 0.f,
                    0.f, 0.f, 0.f, 0.f, 0.f, 0.f, 0.f, 0.f};
#pragma unroll
        for (int s = 0; s < 8; ++s) {   // k 0..127: tap 0 (W0)
            v8bf b0 = *(const v8bf*)&xr0[((2 * s + h) ^ m0) * 8];
            acc = __builtin_amdgcn_mfma_f32_32x32x16_bf16(af[s], b0, acc, 0, 0, 0);
        }
#pragma unroll
        for (int s = 0; s < 8; ++s) {   // k 128..255: tap 1 (W1)
            v8bf b1 = *(const v8bf*)&xr1[((2 * s + h) ^ m1) * 8];
            acc = __builtin_amdgcn_mfma_f32_32x32x16_bf16(af[8 + s], b1, acc, 0, 0, 0);
        }
        // epilogue: bias, leaky, pool adjacent columns (lanes 2u,2u+1), stage to ps
        const int ue = n31 >> 1;
        const bool wlane = !(lane & 1);
#pragma unroll
        for (int q = 0; q < 4; ++q) {
            float p[4];
#pragma unroll
            for (int j = 0; j < 4; ++j) {
                int r = 4 * q + j;
                float y = acc[r] + bias_r[r];
                y = (y >= 0.f) ? y : 0.2f * y;
                float y2 = __shfl_xor(y, 1, 64);
                p[j] = fmaxf(y, y2);
            }
            if (wlane) {
                uint2 v;
                v.x = pack2(p[0], p[1]);
                v.y = pack2(p[2], p[3]);
                // channels 32w + 8q + 4h .. +3, row ue
                *(uint2*)&ps[ue * 128 + w * 32 + 8 * q + 4 * h] = v;
            }
        }
        __syncthreads();
        // coalesced store of pooled tile
        {
            int u_l = tid >> 4, ck = tid & 15;
            int u_g = u0 + nt * 16 + u_l;
            if (u_g < Lp) {
                if (!final) {
                    *(uint4*)&Y[(size_t)u_g * 128 + ck * 8] = *(const uint4*)&ps[u_l * 128 + ck * 8];
                } else if (u_g == 0) {
                    const ushort* p = &ps[ck * 8];
                    float4 o1, o2;
                    o1.x = bf2f(p[0]); o1.y = bf2f(p[1]); o1.z = bf2f(p[2]); o1.w = bf2f(p[3]);
                    o2.x = bf2f(p[4]); o2.y = bf2f(p[5]); o2.z = bf2f(p[6]); o2.w = bf2f(p[7]);
                    *(float4*)&out_f[ck * 8] = o1;
                    *(float4*)&out_f[ck * 8 + 4] = o2;
                }
            }
        }
        __syncthreads();
    }
}

// ---------------------------------------------------------------------------
extern "C" void kernel_launch(void* const* d_in, const int* in_sizes, int n_in,
                              void* d_out, int out_size, void* d_ws, size_t ws_size,
                              hipStream_t stream) {
    const float* x     = (const float*)d_in[0];   // [524288][128]
    const float* depth = (const float*)d_in[1];   // [32][128]
    const float* W     = (const float*)d_in[2];   // [128][256][2]
    const float* b     = (const float*)d_in[3];   // [128]
    const int*   perm  = (const int*)d_in[4];     // [524288]
    float* out = (float*)d_out;                   // [1][128] fp32

    char* ws = (char*)d_ws;
    float*  Bst = (float*)ws;                                     // 18*128 fp32
    ushort* A   = (ushort*)(ws + 16384);                          // 128*256 bf16 = 64 KB
    ushort* R0  = (ushort*)(ws + 16384 + 65536);                  // 262143*256 B
    ushort* R1  = (ushort*)(ws + 16384 + 65536 + (size_t)262143 * 256);  // 131071*256 B

    bias_kernel<<<18, 128, 0, stream>>>(W, b, depth, Bst);
    repack_kernel<<<128, 256, 0, stream>>>(W, A);

    int Lin = 524288;
    const ushort* in = nullptr;
    for (int i = 0; Lin > 1; ++i) {
        int Lp = (Lin - 1) >> 1;
        int final = (Lp == 1) ? 1 : 0;
        ushort* outb = (i & 1) ? R1 : R0;
        int blocks = (Lp + 63) / 64;
        stage_mfma<<<blocks, 256, 0, stream>>>(in, x, perm, A, Bst + i * 128,
                                               outb, out, Lin, Lp, (i == 0) ? 1 : 0, final);
        in = outb;
        Lin = Lp;
    }
}